// Round 6
// baseline (471.447 us; speedup 1.0000x reference)
//
#include <hip/hip_runtime.h>
#include <cstdint>

using u16 = unsigned short;
typedef short bf16x8 __attribute__((ext_vector_type(8)));
typedef float f32x4 __attribute__((ext_vector_type(4)));

__device__ __forceinline__ float bf2f(u16 h) {
    union { unsigned u; float f; } x;
    x.u = ((unsigned)h) << 16;
    return x.f;
}
__device__ __forceinline__ u16 f2bf(float f) {
    union { float f; unsigned u; } x;
    x.f = f;
    unsigned r = x.u + 0x7fffu + ((x.u >> 16) & 1u);
    return (u16)(r >> 16);
}

// async global->LDS, 16B per lane; LDS dest is wave-uniform base + lane*16
__device__ __forceinline__ void gl_lds16(const u16* g, u16* l) {
    __builtin_amdgcn_global_load_lds((const __attribute__((address_space(1))) void*)g,
                                     (__attribute__((address_space(3))) void*)l, 16, 0, 0);
}

#define N1 8192
#define N2 2048
#define C2 256
#define NBK 128           // x-buckets
#define BW 0.0625f        // bucket width: [-4,4]/128
#define MAXCH 6           // max 64-query chunks per bucket

__device__ __forceinline__ int xbucket(float x) {
    int bk = (int)floorf((x + 4.0f) * 16.0f);
    return min(NBK - 1, max(0, bk));
}

// ---------------------------------------------------------------------------
// prep: w0/w1 fp32->bf16, stats zero.
// ---------------------------------------------------------------------------
__global__ __launch_bounds__(256) void prep_misc(const float* __restrict__ w0,
                                                 const float* __restrict__ w1,
                                                 u16* __restrict__ w0b,
                                                 u16* __restrict__ w1b,
                                                 float* __restrict__ stats) {
    int bid = blockIdx.x, tid = threadIdx.x;
    if (bid < 384) {
        int i = bid * 256 + tid;
        w0b[i] = f2bf(w0[i]);
    } else if (bid < 512) {
        int i = (bid - 384) * 256 + tid;
        w1b[i] = f2bf(w1[i]);
    } else {
        for (int i = tid; i < 768; i += 256) stats[i] = 0.0f;
    }
}

// ---------------------------------------------------------------------------
// counting-sort candidates into x-buckets; pack (-2x,-2y,-2z,|p|^2).
// One block per batch. (-2*x exact in fp32 => scan's sq is bit-identical to
// reference (|q|^2+|p|^2) - 2*dot; validated R4/R5.)
// ---------------------------------------------------------------------------
__global__ __launch_bounds__(256) void bucket_cand(const float* __restrict__ xyz2,
                                                   float4* __restrict__ SC,
                                                   int* __restrict__ SIdx,
                                                   int* __restrict__ bstart) {
    __shared__ int cnt[NBK], cur[NBK];
    int b = blockIdx.x, tid = threadIdx.x;
    if (tid < NBK) cnt[tid] = 0;
    __syncthreads();
    for (int i = tid; i < N2; i += 256) {
        float x = xyz2[((long)b * N2 + i) * 3];
        atomicAdd(&cnt[xbucket(x)], 1);
    }
    __syncthreads();
    if (tid == 0) {
        int s = 0;
        for (int k = 0; k < NBK; k++) { int c = cnt[k]; cur[k] = s; cnt[k] = s; s += c; }
    }
    __syncthreads();
    if (tid < NBK) bstart[b * (NBK + 1) + tid] = cnt[tid];
    if (tid == 0) bstart[b * (NBK + 1) + NBK] = N2;
    for (int i = tid; i < N2; i += 256) {
        float x = xyz2[((long)b * N2 + i) * 3 + 0];
        float y = xyz2[((long)b * N2 + i) * 3 + 1];
        float z = xyz2[((long)b * N2 + i) * 3 + 2];
        int pos = atomicAdd(&cur[xbucket(x)], 1);
        float nsq = __fadd_rn(__fadd_rn(__fmul_rn(x, x), __fmul_rn(y, y)), __fmul_rn(z, z));
        SC[(long)b * N2 + pos] = make_float4(-2.0f * x, -2.0f * y, -2.0f * z, nsq);
        SIdx[(long)b * N2 + pos] = i;
    }
}

// ---------------------------------------------------------------------------
// counting-sort queries into x-buckets (indices only). One block per batch.
// ---------------------------------------------------------------------------
__global__ __launch_bounds__(256) void bucket_query(const float* __restrict__ xyz1,
                                                    int* __restrict__ qord,
                                                    int* __restrict__ qstart) {
    __shared__ int cnt[NBK], cur[NBK];
    int b = blockIdx.x, tid = threadIdx.x;
    if (tid < NBK) cnt[tid] = 0;
    __syncthreads();
    for (int i = tid; i < N1; i += 256) {
        float x = xyz1[((long)b * N1 + i) * 3];
        atomicAdd(&cnt[xbucket(x)], 1);
    }
    __syncthreads();
    if (tid == 0) {
        int s = 0;
        for (int k = 0; k < NBK; k++) { int c = cnt[k]; cur[k] = s; cnt[k] = s; s += c; }
    }
    __syncthreads();
    if (tid < NBK) qstart[b * (NBK + 1) + tid] = cnt[tid];
    if (tid == 0) qstart[b * (NBK + 1) + NBK] = N1;
    for (int i = tid; i < N1; i += 256) {
        float x = xyz1[((long)b * N1 + i) * 3];
        int pos = atomicAdd(&cur[xbucket(x)], 1);
        qord[(long)b * N1 + pos] = i;
    }
}

// ---------------------------------------------------------------------------
// [B][C][N] fp32 -> [B][N][dst_stride] bf16 transpose (col offset col_off)
// ---------------------------------------------------------------------------
__global__ __launch_bounds__(256) void transpose_to_bf16(const float* __restrict__ src,
                                                         u16* __restrict__ dst,
                                                         int C, int N, int dst_stride,
                                                         int col_off) {
    __shared__ float tile[32][33];
    int b = blockIdx.z;
    int n0 = blockIdx.x * 32, c0 = blockIdx.y * 32;
    int tx = threadIdx.x & 31, ty = threadIdx.x >> 5;  // 32 x 8
    const float* s = src + (long)b * C * N;
#pragma unroll
    for (int i = 0; i < 4; i++) {
        int c = ty + i * 8;
        tile[c][tx] = s[(long)(c0 + c) * N + n0 + tx];
    }
    __syncthreads();
    u16* d = dst + (long)b * N * dst_stride;
#pragma unroll
    for (int i = 0; i < 4; i++) {
        int n = ty + i * 8;
        d[(long)(n0 + n) * dst_stride + col_off + c0 + tx] = f2bf(tile[tx][n]);
    }
}

// ---------------------------------------------------------------------------
// kNN(3) + interpolation, v6 (R6): bucket-window pruning.
// Block = (bucket, chunk<=64 queries, batch); 4 waves scan absolute-stride-4
// disjoint subsets of an expanding bucket window, each keeping a lexicographic
// (sq, orig_idx) top-3. Wave stops when every lane's (distance to unscanned
// window edge)^2 strictly exceeds its subset 3rd-best (conservative & exact:
// any unscanned candidate c has sq >= dx^2 > subset_b2 >= final_b2, so c
// cannot enter the final top-3 even via ties). 1e-3 edge slack covers binning
// rounding. Final 4-way lexicographic merge == reference selection.
// ---------------------------------------------------------------------------
__global__ __launch_bounds__(256) void knn_interp(const float* __restrict__ xyz1,
                                                  const float4* __restrict__ SC,
                                                  const int* __restrict__ SIdx,
                                                  const int* __restrict__ bstart,
                                                  const int* __restrict__ qord,
                                                  const int* __restrict__ qstart,
                                                  const u16* __restrict__ P2T,
                                                  u16* __restrict__ X) {
    __shared__ float m_d[4][64][3];
    __shared__ int   m_i[4][64][3];
    __shared__ int   s_idx[64][3];
    __shared__ float s_w[64][3];
    __shared__ int   s_qn[64];
    __shared__ int   s_bs[NBK + 1];

    int b = blockIdx.y;
    int bucket = blockIdx.x / MAXCH, chunk = blockIdx.x % MAXCH;
    int q0 = qstart[b * (NBK + 1) + bucket];
    int q1 = qstart[b * (NBK + 1) + bucket + 1];
    int base = q0 + chunk * 64;
    if (base >= q1) return;                    // block-uniform exit
    int qcnt = min(64, q1 - base);

    int tid = threadIdx.x;
    int ql = tid & 63;
    int w = tid >> 6;                          // wave 0..3
    bool valid = ql < qcnt;

    for (int k = tid; k < NBK + 1; k += 256) s_bs[k] = bstart[b * (NBK + 1) + k];

    int n = qord[(long)b * N1 + base + (valid ? ql : 0)];
    if (tid < 64) s_qn[tid] = n;
    float px = xyz1[((long)b * N1 + n) * 3 + 0];
    float py = xyz1[((long)b * N1 + n) * 3 + 1];
    float pz = xyz1[((long)b * N1 + n) * 3 + 2];
    float psq = __fadd_rn(__fadd_rn(__fmul_rn(px, px), __fmul_rn(py, py)), __fmul_rn(pz, pz));
    __syncthreads();

    const float4* sc = SC + (long)b * N2;
    const int* si = SIdx + (long)b * N2;
    float b0 = 1e30f, b1 = 1e30f, b2 = 1e30f;
    int i0 = 0x7fffffff, i1 = 0x7fffffff, i2 = 0x7fffffff;

    auto scan = [&](int s, int e) {
        for (int pos = s + ((w - s) & 3); pos < e; pos += 4) {   // absolute stride class
            float4 p = sc[pos];
            int j = si[pos];
            float u = __fadd_rn(__fadd_rn(__fmul_rn(p.x, px), __fmul_rn(p.y, py)),
                                __fmul_rn(p.z, pz));
            float sq = __fadd_rn(__fadd_rn(psq, p.w), u);
            // lexicographic (sq, j) sorted insert
            bool lt2 = (sq < b2) || (sq == b2 && j < i2);
            bool lt1 = (sq < b1) || (sq == b1 && j < i1);
            bool lt0 = (sq < b0) || (sq == b0 && j < i0);
            i2 = lt2 ? (lt1 ? i1 : j) : i2;
            i1 = lt1 ? (lt0 ? i0 : j) : i1;
            i0 = lt0 ? j : i0;
            float m1 = fmaxf(b0, sq); b0 = fminf(b0, sq);
            float m2 = fmaxf(b1, m1); b1 = fminf(b1, m1);
            b2 = fminf(b2, m2);
        }
    };

    int lo = bucket, hi = bucket;
    scan(s_bs[lo], s_bs[hi + 1]);
    while (true) {
        float tv = valid ? b2 : -1.0f;         // dummy lanes always satisfied
        bool ldone = (lo == 0), rdone = (hi == NBK - 1);
        float L = -4.0f + lo * BW + 1e-3f;
        float R = -4.0f + (hi + 1) * BW - 1e-3f;
        float dl = px - L, dr = R - px;
        bool okl = ldone || (dl > 0.0f && __fmul_rn(dl, dl) > tv);
        bool okr = rdone || (dr > 0.0f && __fmul_rn(dr, dr) > tv);
        int allL = __all(okl), allR = __all(okr);
        if (allL && allR) break;
        int nlo = allL ? lo : max(lo - 2, 0);
        int nhi = allR ? hi : min(hi + 2, NBK - 1);
        if (nlo < lo) scan(s_bs[nlo], s_bs[lo]);
        if (nhi > hi) scan(s_bs[hi + 1], s_bs[nhi + 1]);
        lo = nlo; hi = nhi;
    }

    m_d[w][ql][0] = b0; m_d[w][ql][1] = b1; m_d[w][ql][2] = b2;
    m_i[w][ql][0] = i0; m_i[w][ql][1] = i1; m_i[w][ql][2] = i2;
    __syncthreads();

    // exact 4-way lexicographic merge -> top-3 (wave 0)
    if (tid < 64) {
        float c0 = 1e30f, c1 = 1e30f, c2 = 1e30f;
        int a0 = 0x7fffffff, a1 = 0x7fffffff, a2 = 0x7fffffff;
#pragma unroll
        for (int pp = 0; pp < 4; pp++) {
#pragma unroll
            for (int k = 0; k < 3; k++) {
                float d = m_d[pp][tid][k];
                int ix = m_i[pp][tid][k];
                if (d < c2 || (d == c2 && ix < a2)) {
                    if (d < c1 || (d == c1 && ix < a1)) {
                        c2 = c1; a2 = a1;
                        if (d < c0 || (d == c0 && ix < a0)) { c1 = c0; a1 = a0; c0 = d; a0 = ix; }
                        else                                { c1 = d; a1 = ix; }
                    } else { c2 = d; a2 = ix; }
                }
            }
        }
        float e0 = sqrtf(fmaxf(c0, 0.0f));
        float e1 = sqrtf(fmaxf(c1, 0.0f));
        float e2 = sqrtf(fmaxf(c2, 0.0f));
        float kd0 = fmaxf(e0, 1e-10f), kd1 = fmaxf(e1, 1e-10f), kd2 = fmaxf(e2, 1e-10f);
        float w0 = __fdiv_rn(1.0f, kd0), w1 = __fdiv_rn(1.0f, kd1), w2 = __fdiv_rn(1.0f, kd2);
        float wsum = __fadd_rn(__fadd_rn(w0, w1), w2);
        s_idx[tid][0] = a0; s_idx[tid][1] = a1; s_idx[tid][2] = a2;
        s_w[tid][0] = __fdiv_rn(w0, wsum);
        s_w[tid][1] = __fdiv_rn(w1, wsum);
        s_w[tid][2] = __fdiv_rn(w2, wsum);
    }
    __syncthreads();

    // gather: wave w handles queries p = w, w+4, ...; lane ql covers channels
    // [4ql, 4ql+4) as ushort4 (coalesced 512 B/wave). Row = original n.
    const u16* pbase = P2T + (long)b * N2 * C2;
    for (int p = w; p < qcnt; p += 4) {
        int j0 = s_idx[p][0], j1 = s_idx[p][1], j2 = s_idx[p][2];
        float f0 = s_w[p][0], f1 = s_w[p][1], f2 = s_w[p][2];
        ushort4 r0 = *(const ushort4*)&pbase[(long)j0 * C2 + ql * 4];
        ushort4 r1 = *(const ushort4*)&pbase[(long)j1 * C2 + ql * 4];
        ushort4 r2 = *(const ushort4*)&pbase[(long)j2 * C2 + ql * 4];
        ushort4 o;
        o.x = f2bf(__fadd_rn(__fadd_rn(__fmul_rn(bf2f(r0.x), f0), __fmul_rn(bf2f(r1.x), f1)),
                             __fmul_rn(bf2f(r2.x), f2)));
        o.y = f2bf(__fadd_rn(__fadd_rn(__fmul_rn(bf2f(r0.y), f0), __fmul_rn(bf2f(r1.y), f1)),
                             __fmul_rn(bf2f(r2.y), f2)));
        o.z = f2bf(__fadd_rn(__fadd_rn(__fmul_rn(bf2f(r0.z), f0), __fmul_rn(bf2f(r1.z), f1)),
                             __fmul_rn(bf2f(r2.z), f2)));
        o.w = f2bf(__fadd_rn(__fadd_rn(__fmul_rn(bf2f(r0.w), f0), __fmul_rn(bf2f(r1.w), f1)),
                             __fmul_rn(bf2f(r2.w), f2)));
        *(ushort4*)&X[((long)b * N1 + s_qn[p]) * 384 + 128 + ql * 4] = o;
    }
}

// ---------------------------------------------------------------------------
// bf16 MFMA GEMM (unchanged from R5): 128x128 tile, 4 waves, 16x16x32 MFMA.
// ASYNC: global_load_lds w16 + XOR col swizzle. Else: VGPR staging + fused BN.
// ---------------------------------------------------------------------------
template <int KDIM, bool BN_IN, bool ASYNC>
__global__ __launch_bounds__(256) void gemm_bn(const u16* __restrict__ A,
                                               const u16* __restrict__ Bw,
                                               const float* __restrict__ bias,
                                               const float* __restrict__ g_in_sum,
                                               const float* __restrict__ g_in_ssq,
                                               const float* __restrict__ gamma_in,
                                               const float* __restrict__ beta_in,
                                               u16* __restrict__ Yout, int Ntot,
                                               float* __restrict__ g_out_sum,
                                               float* __restrict__ g_out_ssq) {
    constexpr int LD = ASYNC ? 32 : 40;
    __shared__ __align__(16) u16 Al[128 * LD];
    __shared__ __align__(16) u16 Bl[128 * LD];
    __shared__ float s_stats[256];
    __shared__ float s_scale[BN_IN ? KDIM : 2];
    __shared__ float s_shift[BN_IN ? KDIM : 2];

    int tid = threadIdx.x;
    long s0 = (long)blockIdx.x * 128;
    int o0 = blockIdx.y * 128;

    s_stats[tid] = 0.0f;
    if constexpr (BN_IN) {
        for (int k = tid; k < KDIM; k += 256) {
            float mu = g_in_sum[k] * (1.0f / 65536.0f);
            float var = g_in_ssq[k] * (1.0f / 65536.0f) - mu * mu;
            float rs = rsqrtf(var + 1e-5f);
            float sc = gamma_in[k] * rs;
            s_scale[k] = sc;
            s_shift[k] = beta_in[k] - mu * sc;
        }
    }
    int wid = tid >> 6, lane = tid & 63;
    int wm = wid >> 1, wn = wid & 1;
    int q = lane >> 4, l16 = lane & 15;

    f32x4 acc[4][4];
#pragma unroll
    for (int mi = 0; mi < 4; mi++)
#pragma unroll
        for (int ni = 0; ni < 4; ni++) acc[mi][ni] = (f32x4){0.f, 0.f, 0.f, 0.f};

    int rbase0 = wid * 32;
    int rsub = lane >> 2;
    int colsw = (((lane & 3) ^ (rsub & 3)) << 3);
    const u16* gA0 = A + (s0 + rbase0 + rsub) * KDIM + colsw;
    const u16* gA1 = gA0 + (long)16 * KDIM;
    const u16* gB0 = Bw + (long)(o0 + rbase0 + rsub) * KDIM + colsw;
    const u16* gB1 = gB0 + (long)16 * KDIM;
    u16* lA0 = &Al[rbase0 * 32];
    u16* lA1 = &Al[(rbase0 + 16) * 32];
    u16* lB0 = &Bl[rbase0 * 32];
    u16* lB1 = &Bl[(rbase0 + 16) * 32];
    int qA = ASYNC ? (q ^ (l16 & 3)) : q;

    __syncthreads();

    for (int kt = 0; kt < KDIM; kt += 32) {
        if constexpr (ASYNC) {
            gl_lds16(gA0 + kt, lA0);
            gl_lds16(gA1 + kt, lA1);
            gl_lds16(gB0 + kt, lB0);
            gl_lds16(gB1 + kt, lB1);
        } else {
#pragma unroll
            for (int cc = 0; cc < 2; cc++) {
                int ci = tid + cc * 256;
                int row = ci >> 2;
                int kc = (ci & 3) << 3;
                union { uint4 u; u16 h[8]; } va;
                va.u = *(const uint4*)(A + (s0 + row) * KDIM + kt + kc);
                if constexpr (BN_IN) {
#pragma unroll
                    for (int j = 0; j < 8; j++) {
                        float f = bf2f(va.h[j]);
                        f = fmaxf(fmaf(f, s_scale[kt + kc + j], s_shift[kt + kc + j]), 0.0f);
                        va.h[j] = f2bf(f);
                    }
                }
                *(uint4*)&Al[row * LD + kc] = va.u;
                *(uint4*)&Bl[row * LD + kc] = *(const uint4*)(Bw + (long)(o0 + row) * KDIM + kt + kc);
            }
        }
        __syncthreads();
        bf16x8 af[4], bfr[4];
#pragma unroll
        for (int mi = 0; mi < 4; mi++)
            af[mi] = *(const bf16x8*)&Al[(wm * 64 + mi * 16 + l16) * LD + qA * 8];
#pragma unroll
        for (int ni = 0; ni < 4; ni++)
            bfr[ni] = *(const bf16x8*)&Bl[(wn * 64 + ni * 16 + l16) * LD + qA * 8];
#pragma unroll
        for (int mi = 0; mi < 4; mi++)
#pragma unroll
            for (int ni = 0; ni < 4; ni++)
                acc[mi][ni] = __builtin_amdgcn_mfma_f32_16x16x32_bf16(af[mi], bfr[ni],
                                                                      acc[mi][ni], 0, 0, 0);
        __syncthreads();
    }

#pragma unroll
    for (int ni = 0; ni < 4; ni++) {
        int coll = wn * 64 + ni * 16 + l16;
        int col = o0 + coll;
        float bz = bias[col];
        float s1 = 0.0f, s2 = 0.0f;
#pragma unroll
        for (int mi = 0; mi < 4; mi++) {
#pragma unroll
            for (int r = 0; r < 4; r++) {
                float v = acc[mi][ni][r] + bz;
                s1 += v;
                s2 += v * v;
                long row = s0 + wm * 64 + mi * 16 + q * 4 + r;
                Yout[row * Ntot + col] = f2bf(v);
            }
        }
        s1 += __shfl_xor(s1, 16, 64);
        s1 += __shfl_xor(s1, 32, 64);
        s2 += __shfl_xor(s2, 16, 64);
        s2 += __shfl_xor(s2, 32, 64);
        if (q == 0) {
            atomicAdd(&s_stats[coll], s1);
            atomicAdd(&s_stats[128 + coll], s2);
        }
    }
    __syncthreads();
    if (tid < 128) {
        atomicAdd(&g_out_sum[o0 + tid], s_stats[tid]);
        atomicAdd(&g_out_ssq[o0 + tid], s_stats[128 + tid]);
    }
}

// ---------------------------------------------------------------------------
// final BN+ReLU + transpose to [B][128][N1] fp32 (Y1 bf16, 16B reads)
// ---------------------------------------------------------------------------
__global__ __launch_bounds__(256) void finalize_k(const u16* __restrict__ Y1,
                                                  const float* __restrict__ g_sum,
                                                  const float* __restrict__ g_ssq,
                                                  const float* __restrict__ gamma,
                                                  const float* __restrict__ beta,
                                                  float* __restrict__ out) {
    __shared__ float s_scale[128], s_shift[128];
    int tid = threadIdx.x;
    if (tid < 128) {
        float mu = g_sum[tid] * (1.0f / 65536.0f);
        float var = g_ssq[tid] * (1.0f / 65536.0f) - mu * mu;
        float rs = rsqrtf(var + 1e-5f);
        float sc = gamma[tid] * rs;
        s_scale[tid] = sc;
        s_shift[tid] = beta[tid] - mu * sc;
    }
    __syncthreads();
    long s = (long)blockIdx.x * 256 + tid;
    int b = (int)(s >> 13);
    int n = (int)(s & 8191);
    const u16* yrow = Y1 + s * 128;
    float* obase = out + (long)b * 128 * 8192 + n;
#pragma unroll
    for (int oc = 0; oc < 128; oc += 8) {
        union { uint4 u; u16 h[8]; } va;
        va.u = *(const uint4*)&yrow[oc];
#pragma unroll
        for (int k = 0; k < 8; k++) {
            int o = oc + k;
            float v = fmaxf(fmaf(bf2f(va.h[k]), s_scale[o], s_shift[o]), 0.0f);
            obase[(long)o * 8192] = v;
        }
    }
}

// ---------------------------------------------------------------------------
// launch
// ---------------------------------------------------------------------------
extern "C" void kernel_launch(void* const* d_in, const int* in_sizes, int n_in,
                              void* d_out, int out_size, void* d_ws, size_t ws_size,
                              hipStream_t stream) {
    const float* xyz1    = (const float*)d_in[0];
    const float* xyz2    = (const float*)d_in[1];
    const float* points1 = (const float*)d_in[2];
    const float* points2 = (const float*)d_in[3];
    const float* w0 = (const float*)d_in[4];
    const float* b0 = (const float*)d_in[5];
    const float* gamma0 = (const float*)d_in[6];
    const float* beta0 = (const float*)d_in[7];
    const float* w1 = (const float*)d_in[8];
    const float* b1 = (const float*)d_in[9];
    const float* gamma1 = (const float*)d_in[10];
    const float* beta1 = (const float*)d_in[11];
    float* out = (float*)d_out;

    char* ws = (char*)d_ws;
    u16* X       = (u16*)(ws + 0);             // 65536 x 384 bf16 = 50,331,648
    u16* P2T     = (u16*)(ws + 50331648);      // 8,388,608
    u16* w0b     = (u16*)(ws + 58720256);      // 196,608
    u16* w1b     = (u16*)(ws + 58916864);      // 65,536
    u16* Y0      = (u16*)(ws + 58982400);      // 33,554,432
    float4* SC   = (float4*)(ws + 92536832);   // 8x2048x16 = 262,144
    int* SIdx    = (int*)(ws + 92798976);      // 65,536
    int* qord    = (int*)(ws + 92864512);      // 262,144
    int* bstart  = (int*)(ws + 93126656);      // 8,192 (padded)
    int* qstart  = (int*)(ws + 93134848);      // 8,192 (padded)
    u16* Y1b     = (u16*)(ws + 93143040);      // 16,777,216
    float* stats = (float*)(ws + 109920256);   // 3,072
    if (ws_size < 109923328) return;
    float* gsum0 = stats;
    float* gss0  = stats + 256;
    float* gsum1 = stats + 512;
    float* gss1  = stats + 640;

    prep_misc<<<513, 256, 0, stream>>>(w0, w1, w0b, w1b, stats);
    bucket_cand<<<8, 256, 0, stream>>>(xyz2, SC, SIdx, bstart);
    bucket_query<<<8, 256, 0, stream>>>(xyz1, qord, qstart);
    transpose_to_bf16<<<dim3(256, 4, 8), 256, 0, stream>>>(points1, X, 128, 8192, 384, 0);
    transpose_to_bf16<<<dim3(64, 8, 8), 256, 0, stream>>>(points2, P2T, 256, 2048, 256, 0);
    knn_interp<<<dim3(NBK * MAXCH, 8), 256, 0, stream>>>(xyz1, SC, SIdx, bstart,
                                                         qord, qstart, P2T, X);
    gemm_bn<384, false, true><<<dim3(512, 2), 256, 0, stream>>>(
        X, w0b, b0, nullptr, nullptr, nullptr, nullptr, Y0, 256, gsum0, gss0);
    gemm_bn<256, true, false><<<dim3(512, 1), 256, 0, stream>>>(
        Y0, w1b, b1, gsum0, gss0, gamma0, beta0, Y1b, 128, gsum1, gss1);
    finalize_k<<<256, 256, 0, stream>>>(Y1b, gsum1, gss1, gamma1, beta1, out);
}

// Round 7
// 268.223 us; speedup vs baseline: 1.7577x; 1.7577x over previous
//
#include <hip/hip_runtime.h>
#include <cstdint>

using u16 = unsigned short;
typedef short bf16x8 __attribute__((ext_vector_type(8)));
typedef float f32x4 __attribute__((ext_vector_type(4)));

__device__ __forceinline__ float bf2f(u16 h) {
    union { unsigned u; float f; } x;
    x.u = ((unsigned)h) << 16;
    return x.f;
}
__device__ __forceinline__ u16 f2bf(float f) {
    union { float f; unsigned u; } x;
    x.f = f;
    unsigned r = x.u + 0x7fffu + ((x.u >> 16) & 1u);
    return (u16)(r >> 16);
}

// async global->LDS, 16B per lane; LDS dest is wave-uniform base + lane*16
__device__ __forceinline__ void gl_lds16(const u16* g, u16* l) {
    __builtin_amdgcn_global_load_lds((const __attribute__((address_space(1))) void*)g,
                                     (__attribute__((address_space(3))) void*)l, 16, 0, 0);
}

#define N1 8192
#define N2 2048
#define C2 256

// ---------------------------------------------------------------------------
// prep: w0/w1 fp32->bf16, stats zero.
// ---------------------------------------------------------------------------
__global__ __launch_bounds__(256) void prep_misc(const float* __restrict__ w0,
                                                 const float* __restrict__ w1,
                                                 u16* __restrict__ w0b,
                                                 u16* __restrict__ w1b,
                                                 float* __restrict__ stats) {
    int bid = blockIdx.x, tid = threadIdx.x;
    if (bid < 384) {
        int i = bid * 256 + tid;
        w0b[i] = f2bf(w0[i]);
    } else if (bid < 512) {
        int i = (bid - 384) * 256 + tid;
        w1b[i] = f2bf(w1[i]);
    } else {
        for (int i = tid; i < 768; i += 256) stats[i] = 0.0f;
    }
}

// ---------------------------------------------------------------------------
// [B][C][N] fp32 -> [B][N][dst_stride] bf16 transpose (col offset col_off)
// ---------------------------------------------------------------------------
__global__ __launch_bounds__(256) void transpose_to_bf16(const float* __restrict__ src,
                                                         u16* __restrict__ dst,
                                                         int C, int N, int dst_stride,
                                                         int col_off) {
    __shared__ float tile[32][33];
    int b = blockIdx.z;
    int n0 = blockIdx.x * 32, c0 = blockIdx.y * 32;
    int tx = threadIdx.x & 31, ty = threadIdx.x >> 5;  // 32 x 8
    const float* s = src + (long)b * C * N;
#pragma unroll
    for (int i = 0; i < 4; i++) {
        int c = ty + i * 8;
        tile[c][tx] = s[(long)(c0 + c) * N + n0 + tx];
    }
    __syncthreads();
    u16* d = dst + (long)b * N * dst_stride;
#pragma unroll
    for (int i = 0; i < 4; i++) {
        int n = ty + i * 8;
        d[(long)(n0 + n) * dst_stride + col_off + c0 + tx] = f2bf(tile[tx][n]);
    }
}

// ---------------------------------------------------------------------------
// kNN(3) + inverse-distance interpolation — R3 variant, REVERTED VERBATIM.
// Measured 80.6 us (R3 bench). History (duration-truth):
//   R3 LDS+cascade: 80.6 | R4 scalar-load net: 89.0 | R5 minmax net: 93.5 |
//   R6 bucket-pruned: ~290 (latency-bound serial uniform loads).
// Do not re-tune the scan instruction mix without new disasm evidence.
// Block = 64 queries x 4 scanner waves (each scans 512 of 2048 candidates
// by squared distance), 12-way (sq,idx) lexicographic merge in LDS, sqrt
// only for the 3 winners. Grid 128x8; gather vectorized ushort4.
// ---------------------------------------------------------------------------
__global__ __launch_bounds__(256) void knn_interp(const float* __restrict__ xyz1,
                                                  const float* __restrict__ xyz2,
                                                  const u16* __restrict__ P2T,  // [B][N2][C2]
                                                  u16* __restrict__ X) {       // [B*N1][384]
    __shared__ float4 pts[N2];          // 32768 B
    __shared__ float m_d[4][64][3];     // partial top-3 (squared dist)
    __shared__ int   m_i[4][64][3];
    __shared__ int   s_idx[64][3];
    __shared__ float s_w[64][3];
    int b = blockIdx.y;
    int n0 = blockIdx.x * 64;
    int tid = threadIdx.x;
    int ql = tid & 63;       // query within block
    int part = tid >> 6;     // candidate partition 0..3 (== wave id)

    // stage xyz2[b] into LDS with squared norm (ref formula, no FMA)
    for (int j = tid; j < N2; j += 256) {
        float x = xyz2[((long)b * N2 + j) * 3 + 0];
        float y = xyz2[((long)b * N2 + j) * 3 + 1];
        float z = xyz2[((long)b * N2 + j) * 3 + 2];
        float nsq = __fadd_rn(__fadd_rn(__fmul_rn(x, x), __fmul_rn(y, y)), __fmul_rn(z, z));
        pts[j] = make_float4(x, y, z, nsq);
    }
    __syncthreads();

    int n = n0 + ql;
    float px = xyz1[((long)b * N1 + n) * 3 + 0];
    float py = xyz1[((long)b * N1 + n) * 3 + 1];
    float pz = xyz1[((long)b * N1 + n) * 3 + 2];
    float psq = __fadd_rn(__fadd_rn(__fmul_rn(px, px), __fmul_rn(py, py)), __fmul_rn(pz, pz));

    // scan 512 candidates by squared distance (sqrt monotonic; exact d after
    // merge). Within-part ascending j + strict < preserves lower-index ties.
    float b0 = 1e30f, b1 = 1e30f, b2 = 1e30f;
    int i0 = 0, i1 = 0, i2 = 0;
    int jbeg = part * (N2 / 4);
#pragma unroll 8
    for (int jj = 0; jj < N2 / 4; jj++) {
        int j = jbeg + jj;
        float4 p = pts[j];  // j uniform across the wave -> LDS broadcast
        float dot = __fadd_rn(__fadd_rn(__fmul_rn(px, p.x), __fmul_rn(py, p.y)),
                              __fmul_rn(pz, p.z));
        float sq = __fsub_rn(__fadd_rn(psq, p.w), __fmul_rn(2.0f, dot));
        if (sq < b2) {
            if (sq < b1) {
                b2 = b1; i2 = i1;
                if (sq < b0) { b1 = b0; i1 = i0; b0 = sq; i0 = j; }
                else         { b1 = sq; i1 = j; }
            } else { b2 = sq; i2 = j; }
        }
    }
    m_d[part][ql][0] = b0; m_d[part][ql][1] = b1; m_d[part][ql][2] = b2;
    m_i[part][ql][0] = i0; m_i[part][ql][1] = i1; m_i[part][ql][2] = i2;
    __syncthreads();

    // merge 4x3 partials -> top-3, lexicographic (sq, idx). Parts scan
    // disjoint ascending ranges so all 12 entries are distinct candidates.
    if (tid < 64) {
        float c0 = 1e30f, c1 = 1e30f, c2 = 1e30f;
        int a0 = 0x7fffffff, a1 = 0x7fffffff, a2 = 0x7fffffff;
#pragma unroll
        for (int pp = 0; pp < 4; pp++) {
#pragma unroll
            for (int k = 0; k < 3; k++) {
                float d = m_d[pp][tid][k];
                int ix = m_i[pp][tid][k];
                if (d < c2 || (d == c2 && ix < a2)) {
                    if (d < c1 || (d == c1 && ix < a1)) {
                        c2 = c1; a2 = a1;
                        if (d < c0 || (d == c0 && ix < a0)) { c1 = c0; a1 = a0; c0 = d; a0 = ix; }
                        else                                { c1 = d; a1 = ix; }
                    } else { c2 = d; a2 = ix; }
                }
            }
        }
        // exact reference math for winners: d = sqrt(max(sq,0)), clamp 1e-10
        float e0 = sqrtf(fmaxf(c0, 0.0f));
        float e1 = sqrtf(fmaxf(c1, 0.0f));
        float e2 = sqrtf(fmaxf(c2, 0.0f));
        float kd0 = fmaxf(e0, 1e-10f), kd1 = fmaxf(e1, 1e-10f), kd2 = fmaxf(e2, 1e-10f);
        float w0 = __fdiv_rn(1.0f, kd0), w1 = __fdiv_rn(1.0f, kd1), w2 = __fdiv_rn(1.0f, kd2);
        float wsum = __fadd_rn(__fadd_rn(w0, w1), w2);
        s_idx[tid][0] = a0; s_idx[tid][1] = a1; s_idx[tid][2] = a2;
        s_w[tid][0] = __fdiv_rn(w0, wsum);
        s_w[tid][1] = __fdiv_rn(w1, wsum);
        s_w[tid][2] = __fdiv_rn(w2, wsum);
    }
    __syncthreads();

    // gather: wave w handles queries p = w, w+4, ...; lane l covers channels
    // [4l, 4l+4) as ushort4 (8 B/lane, coalesced 512 B/wave).
    int l = tid & 63;
    const u16* base = P2T + (long)b * N2 * C2;
    for (int p = part; p < 64; p += 4) {
        int j0 = s_idx[p][0], j1 = s_idx[p][1], j2 = s_idx[p][2];  // broadcast
        float f0 = s_w[p][0], f1 = s_w[p][1], f2 = s_w[p][2];
        ushort4 r0 = *(const ushort4*)&base[(long)j0 * C2 + l * 4];
        ushort4 r1 = *(const ushort4*)&base[(long)j1 * C2 + l * 4];
        ushort4 r2 = *(const ushort4*)&base[(long)j2 * C2 + l * 4];
        ushort4 o;
        o.x = f2bf(__fadd_rn(__fadd_rn(__fmul_rn(bf2f(r0.x), f0), __fmul_rn(bf2f(r1.x), f1)),
                             __fmul_rn(bf2f(r2.x), f2)));
        o.y = f2bf(__fadd_rn(__fadd_rn(__fmul_rn(bf2f(r0.y), f0), __fmul_rn(bf2f(r1.y), f1)),
                             __fmul_rn(bf2f(r2.y), f2)));
        o.z = f2bf(__fadd_rn(__fadd_rn(__fmul_rn(bf2f(r0.z), f0), __fmul_rn(bf2f(r1.z), f1)),
                             __fmul_rn(bf2f(r2.z), f2)));
        o.w = f2bf(__fadd_rn(__fadd_rn(__fmul_rn(bf2f(r0.w), f0), __fmul_rn(bf2f(r1.w), f1)),
                             __fmul_rn(bf2f(r2.w), f2)));
        *(ushort4*)&X[(long)(b * N1 + n0 + p) * 384 + 128 + l * 4] = o;
    }
}

// ---------------------------------------------------------------------------
// bf16 MFMA GEMM (R5 form): 128x128 tile, 4 waves, 16x16x32 MFMA.
// ASYNC: global_load_lds w16 + XOR col swizzle. Else: VGPR staging + fused BN.
// Epilogue: bias add, bf16 store, per-channel sum/sumsq via atomics.
// ---------------------------------------------------------------------------
template <int KDIM, bool BN_IN, bool ASYNC>
__global__ __launch_bounds__(256) void gemm_bn(const u16* __restrict__ A,
                                               const u16* __restrict__ Bw,
                                               const float* __restrict__ bias,
                                               const float* __restrict__ g_in_sum,
                                               const float* __restrict__ g_in_ssq,
                                               const float* __restrict__ gamma_in,
                                               const float* __restrict__ beta_in,
                                               u16* __restrict__ Yout, int Ntot,
                                               float* __restrict__ g_out_sum,
                                               float* __restrict__ g_out_ssq) {
    constexpr int LD = ASYNC ? 32 : 40;
    __shared__ __align__(16) u16 Al[128 * LD];
    __shared__ __align__(16) u16 Bl[128 * LD];
    __shared__ float s_stats[256];
    __shared__ float s_scale[BN_IN ? KDIM : 2];
    __shared__ float s_shift[BN_IN ? KDIM : 2];

    int tid = threadIdx.x;
    long s0 = (long)blockIdx.x * 128;
    int o0 = blockIdx.y * 128;

    s_stats[tid] = 0.0f;
    if constexpr (BN_IN) {
        for (int k = tid; k < KDIM; k += 256) {
            float mu = g_in_sum[k] * (1.0f / 65536.0f);
            float var = g_in_ssq[k] * (1.0f / 65536.0f) - mu * mu;
            float rs = rsqrtf(var + 1e-5f);
            float sc = gamma_in[k] * rs;
            s_scale[k] = sc;
            s_shift[k] = beta_in[k] - mu * sc;
        }
    }
    int wid = tid >> 6, lane = tid & 63;
    int wm = wid >> 1, wn = wid & 1;
    int q = lane >> 4, l16 = lane & 15;

    f32x4 acc[4][4];
#pragma unroll
    for (int mi = 0; mi < 4; mi++)
#pragma unroll
        for (int ni = 0; ni < 4; ni++) acc[mi][ni] = (f32x4){0.f, 0.f, 0.f, 0.f};

    int rbase0 = wid * 32;
    int rsub = lane >> 2;
    int colsw = (((lane & 3) ^ (rsub & 3)) << 3);
    const u16* gA0 = A + (s0 + rbase0 + rsub) * KDIM + colsw;
    const u16* gA1 = gA0 + (long)16 * KDIM;
    const u16* gB0 = Bw + (long)(o0 + rbase0 + rsub) * KDIM + colsw;
    const u16* gB1 = gB0 + (long)16 * KDIM;
    u16* lA0 = &Al[rbase0 * 32];
    u16* lA1 = &Al[(rbase0 + 16) * 32];
    u16* lB0 = &Bl[rbase0 * 32];
    u16* lB1 = &Bl[(rbase0 + 16) * 32];
    int qA = ASYNC ? (q ^ (l16 & 3)) : q;

    __syncthreads();

    for (int kt = 0; kt < KDIM; kt += 32) {
        if constexpr (ASYNC) {
            gl_lds16(gA0 + kt, lA0);
            gl_lds16(gA1 + kt, lA1);
            gl_lds16(gB0 + kt, lB0);
            gl_lds16(gB1 + kt, lB1);
        } else {
#pragma unroll
            for (int cc = 0; cc < 2; cc++) {
                int ci = tid + cc * 256;
                int row = ci >> 2;
                int kc = (ci & 3) << 3;
                union { uint4 u; u16 h[8]; } va;
                va.u = *(const uint4*)(A + (s0 + row) * KDIM + kt + kc);
                if constexpr (BN_IN) {
#pragma unroll
                    for (int j = 0; j < 8; j++) {
                        float f = bf2f(va.h[j]);
                        f = fmaxf(fmaf(f, s_scale[kt + kc + j], s_shift[kt + kc + j]), 0.0f);
                        va.h[j] = f2bf(f);
                    }
                }
                *(uint4*)&Al[row * LD + kc] = va.u;
                *(uint4*)&Bl[row * LD + kc] = *(const uint4*)(Bw + (long)(o0 + row) * KDIM + kt + kc);
            }
        }
        __syncthreads();
        bf16x8 af[4], bfr[4];
#pragma unroll
        for (int mi = 0; mi < 4; mi++)
            af[mi] = *(const bf16x8*)&Al[(wm * 64 + mi * 16 + l16) * LD + qA * 8];
#pragma unroll
        for (int ni = 0; ni < 4; ni++)
            bfr[ni] = *(const bf16x8*)&Bl[(wn * 64 + ni * 16 + l16) * LD + qA * 8];
#pragma unroll
        for (int mi = 0; mi < 4; mi++)
#pragma unroll
            for (int ni = 0; ni < 4; ni++)
                acc[mi][ni] = __builtin_amdgcn_mfma_f32_16x16x32_bf16(af[mi], bfr[ni],
                                                                      acc[mi][ni], 0, 0, 0);
        __syncthreads();
    }

#pragma unroll
    for (int ni = 0; ni < 4; ni++) {
        int coll = wn * 64 + ni * 16 + l16;
        int col = o0 + coll;
        float bz = bias[col];
        float s1 = 0.0f, s2 = 0.0f;
#pragma unroll
        for (int mi = 0; mi < 4; mi++) {
#pragma unroll
            for (int r = 0; r < 4; r++) {
                float v = acc[mi][ni][r] + bz;
                s1 += v;
                s2 += v * v;
                long row = s0 + wm * 64 + mi * 16 + q * 4 + r;
                Yout[row * Ntot + col] = f2bf(v);
            }
        }
        s1 += __shfl_xor(s1, 16, 64);
        s1 += __shfl_xor(s1, 32, 64);
        s2 += __shfl_xor(s2, 16, 64);
        s2 += __shfl_xor(s2, 32, 64);
        if (q == 0) {
            atomicAdd(&s_stats[coll], s1);
            atomicAdd(&s_stats[128 + coll], s2);
        }
    }
    __syncthreads();
    if (tid < 128) {
        atomicAdd(&g_out_sum[o0 + tid], s_stats[tid]);
        atomicAdd(&g_out_ssq[o0 + tid], s_stats[128 + tid]);
    }
}

// ---------------------------------------------------------------------------
// final BN+ReLU + transpose to [B][128][N1] fp32 (Y1 bf16, 16B reads)
// ---------------------------------------------------------------------------
__global__ __launch_bounds__(256) void finalize_k(const u16* __restrict__ Y1,
                                                  const float* __restrict__ g_sum,
                                                  const float* __restrict__ g_ssq,
                                                  const float* __restrict__ gamma,
                                                  const float* __restrict__ beta,
                                                  float* __restrict__ out) {
    __shared__ float s_scale[128], s_shift[128];
    int tid = threadIdx.x;
    if (tid < 128) {
        float mu = g_sum[tid] * (1.0f / 65536.0f);
        float var = g_ssq[tid] * (1.0f / 65536.0f) - mu * mu;
        float rs = rsqrtf(var + 1e-5f);
        float sc = gamma[tid] * rs;
        s_scale[tid] = sc;
        s_shift[tid] = beta[tid] - mu * sc;
    }
    __syncthreads();
    long s = (long)blockIdx.x * 256 + tid;
    int b = (int)(s >> 13);
    int n = (int)(s & 8191);
    const u16* yrow = Y1 + s * 128;
    float* obase = out + (long)b * 128 * 8192 + n;
#pragma unroll
    for (int oc = 0; oc < 128; oc += 8) {
        union { uint4 u; u16 h[8]; } va;
        va.u = *(const uint4*)&yrow[oc];
#pragma unroll
        for (int k = 0; k < 8; k++) {
            int o = oc + k;
            float v = fmaxf(fmaf(bf2f(va.h[k]), s_scale[o], s_shift[o]), 0.0f);
            obase[(long)o * 8192] = v;
        }
    }
}

// ---------------------------------------------------------------------------
// launch
// ---------------------------------------------------------------------------
extern "C" void kernel_launch(void* const* d_in, const int* in_sizes, int n_in,
                              void* d_out, int out_size, void* d_ws, size_t ws_size,
                              hipStream_t stream) {
    const float* xyz1    = (const float*)d_in[0];
    const float* xyz2    = (const float*)d_in[1];
    const float* points1 = (const float*)d_in[2];
    const float* points2 = (const float*)d_in[3];
    const float* w0 = (const float*)d_in[4];
    const float* b0 = (const float*)d_in[5];
    const float* gamma0 = (const float*)d_in[6];
    const float* beta0 = (const float*)d_in[7];
    const float* w1 = (const float*)d_in[8];
    const float* b1 = (const float*)d_in[9];
    const float* gamma1 = (const float*)d_in[10];
    const float* beta1 = (const float*)d_in[11];
    float* out = (float*)d_out;

    char* ws = (char*)d_ws;
    u16* X       = (u16*)(ws + 0);             // 65536 x 384 bf16 = 50,331,648
    u16* P2T     = (u16*)(ws + 50331648);      // 8,388,608
    u16* w0b     = (u16*)(ws + 58720256);      // 196,608
    u16* w1b     = (u16*)(ws + 58916864);      // 65,536
    u16* Y0      = (u16*)(ws + 58982400);      // 33,554,432
    u16* Y1b     = (u16*)(ws + 92536832);      // 16,777,216
    float* stats = (float*)(ws + 109314048);   // 3,072
    if (ws_size < 109317120) return;
    float* gsum0 = stats;
    float* gss0  = stats + 256;
    float* gsum1 = stats + 512;
    float* gss1  = stats + 640;

    prep_misc<<<513, 256, 0, stream>>>(w0, w1, w0b, w1b, stats);
    transpose_to_bf16<<<dim3(256, 4, 8), 256, 0, stream>>>(points1, X, 128, 8192, 384, 0);
    transpose_to_bf16<<<dim3(64, 8, 8), 256, 0, stream>>>(points2, P2T, 256, 2048, 256, 0);
    knn_interp<<<dim3(128, 8), 256, 0, stream>>>(xyz1, xyz2, P2T, X);
    gemm_bn<384, false, true><<<dim3(512, 2), 256, 0, stream>>>(
        X, w0b, b0, nullptr, nullptr, nullptr, nullptr, Y0, 256, gsum0, gss0);
    gemm_bn<256, true, false><<<dim3(512, 1), 256, 0, stream>>>(
        Y0, w1b, b1, gsum0, gss0, gamma0, beta0, Y1b, 128, gsum1, gss1);
    finalize_k<<<256, 256, 0, stream>>>(Y1b, gsum1, gss1, gamma1, beta1, out);
}

// Round 8
// 258.039 us; speedup vs baseline: 1.8270x; 1.0395x over previous
//
#include <hip/hip_runtime.h>
#include <cstdint>

using u16 = unsigned short;
typedef short bf16x8 __attribute__((ext_vector_type(8)));
typedef float f32x4 __attribute__((ext_vector_type(4)));

__device__ __forceinline__ float bf2f(u16 h) {
    union { unsigned u; float f; } x;
    x.u = ((unsigned)h) << 16;
    return x.f;
}
__device__ __forceinline__ u16 f2bf(float f) {
    union { float f; unsigned u; } x;
    x.f = f;
    unsigned r = x.u + 0x7fffu + ((x.u >> 16) & 1u);
    return (u16)(r >> 16);
}

// async global->LDS, 16B per lane; LDS dest is wave-uniform base + lane*16
__device__ __forceinline__ void gl_lds16(const u16* g, u16* l) {
    __builtin_amdgcn_global_load_lds((const __attribute__((address_space(1))) void*)g,
                                     (__attribute__((address_space(3))) void*)l, 16, 0, 0);
}

#define N1 8192
#define N2 2048
#define C2 256

// ---------------------------------------------------------------------------
// fused preproc (R8): points1/points2 transposes + w0/w1 cvt + stats zero in
// ONE dispatch (was 3 kernels + implicit gaps). Transpose tile: 32x32 via LDS.
// ---------------------------------------------------------------------------
__device__ __forceinline__ void tr_tile(const float* __restrict__ src,
                                        u16* __restrict__ dst,
                                        int C, int N, int ds, int b, int n0, int c0,
                                        int tid, float (*tile)[33]) {
    int tx = tid & 31, ty = tid >> 5;  // 32 x 8
    const float* s = src + (long)b * C * N;
#pragma unroll
    for (int i = 0; i < 4; i++) {
        int c = ty + i * 8;
        tile[c][tx] = s[(long)(c0 + c) * N + n0 + tx];
    }
    __syncthreads();
    u16* d = dst + (long)b * N * ds;
#pragma unroll
    for (int i = 0; i < 4; i++) {
        int n = ty + i * 8;
        d[(long)(n0 + n) * ds + c0 + tx] = f2bf(tile[tx][n]);
    }
}

__global__ __launch_bounds__(256) void preproc(const float* __restrict__ w0,
                                               const float* __restrict__ w1,
                                               const float* __restrict__ points1,
                                               const float* __restrict__ points2,
                                               u16* __restrict__ w0b,
                                               u16* __restrict__ w1b,
                                               u16* __restrict__ X,
                                               u16* __restrict__ P2T,
                                               float* __restrict__ stats) {
    __shared__ float tile[32][33];
    int bid = blockIdx.x, tid = threadIdx.x;
    if (bid < 8192) {
        // points1 [8][128][8192] -> X[.][0:128] (ds=384): 256 nb x 4 cb x 8 b
        int nb = bid & 255, cb = (bid >> 8) & 3, b = bid >> 10;
        tr_tile(points1, X, 128, 8192, 384, b, nb * 32, cb * 32, tid, tile);
    } else if (bid < 12288) {
        // points2 [8][256][2048] -> P2T (ds=256): 64 nb x 8 cb x 8 b
        int t = bid - 8192;
        int nb = t & 63, cb = (t >> 6) & 7, b = t >> 9;
        tr_tile(points2, P2T, 256, 2048, 256, b, nb * 32, cb * 32, tid, tile);
    } else if (bid < 12672) {
        int i = (bid - 12288) * 256 + tid;
        w0b[i] = f2bf(w0[i]);
    } else if (bid < 12800) {
        int i = (bid - 12672) * 256 + tid;
        w1b[i] = f2bf(w1[i]);
    } else {
        for (int i = tid; i < 768; i += 256) stats[i] = 0.0f;
    }
}

// ---------------------------------------------------------------------------
// kNN(3) + interpolation — R3 inner loop VERBATIM (measured 80.6us; R4/R5/R6
// rewrites all regressed — do not touch the scan body). R8 change: stage xyz2
// in TWO 1024-point halves -> LDS 40.4KB -> ~24KB, blocks/CU 3 -> 6,
// waves/CU 12 -> 24. Each wave's candidate set is still a disjoint
// ascending-index union (half0 range then half1 range), strict < keeps the
// earlier index on ties == reference semantics; merge unchanged.
// ---------------------------------------------------------------------------
__global__ __launch_bounds__(256) void knn_interp(const float* __restrict__ xyz1,
                                                  const float* __restrict__ xyz2,
                                                  const u16* __restrict__ P2T,  // [B][N2][C2]
                                                  u16* __restrict__ X) {       // [B*N1][384]
    __shared__ float4 pts[N2 / 2];      // 16384 B (half-staged)
    __shared__ float m_d[4][64][3];     // partial top-3 (squared dist)
    __shared__ int   m_i[4][64][3];
    __shared__ int   s_idx[64][3];
    __shared__ float s_w[64][3];
    int b = blockIdx.y;
    int n0 = blockIdx.x * 64;
    int tid = threadIdx.x;
    int ql = tid & 63;       // query within block
    int part = tid >> 6;     // candidate partition 0..3 (== wave id)

    int n = n0 + ql;
    float px = xyz1[((long)b * N1 + n) * 3 + 0];
    float py = xyz1[((long)b * N1 + n) * 3 + 1];
    float pz = xyz1[((long)b * N1 + n) * 3 + 2];
    float psq = __fadd_rn(__fadd_rn(__fmul_rn(px, px), __fmul_rn(py, py)), __fmul_rn(pz, pz));

    float b0 = 1e30f, b1 = 1e30f, b2 = 1e30f;
    int i0 = 0, i1 = 0, i2 = 0;

    for (int half = 0; half < 2; half++) {
        // stage this half of xyz2[b] with squared norm (ref formula, no FMA)
        for (int j = tid; j < N2 / 2; j += 256) {
            int jg = half * (N2 / 2) + j;
            float x = xyz2[((long)b * N2 + jg) * 3 + 0];
            float y = xyz2[((long)b * N2 + jg) * 3 + 1];
            float z = xyz2[((long)b * N2 + jg) * 3 + 2];
            float nsq = __fadd_rn(__fadd_rn(__fmul_rn(x, x), __fmul_rn(y, y)), __fmul_rn(z, z));
            pts[j] = make_float4(x, y, z, nsq);
        }
        __syncthreads();

        // scan this wave's 256-candidate quarter of the half (R3 body verbatim)
        int jbeg = half * (N2 / 2) + part * (N2 / 8);
        const float4* lp = &pts[part * (N2 / 8)];
#pragma unroll 8
        for (int jj = 0; jj < N2 / 8; jj++) {
            int j = jbeg + jj;
            float4 p = lp[jj];  // wave-uniform -> LDS broadcast
            float dot = __fadd_rn(__fadd_rn(__fmul_rn(px, p.x), __fmul_rn(py, p.y)),
                                  __fmul_rn(pz, p.z));
            float sq = __fsub_rn(__fadd_rn(psq, p.w), __fmul_rn(2.0f, dot));
            if (sq < b2) {
                if (sq < b1) {
                    b2 = b1; i2 = i1;
                    if (sq < b0) { b1 = b0; i1 = i0; b0 = sq; i0 = j; }
                    else         { b1 = sq; i1 = j; }
                } else { b2 = sq; i2 = j; }
            }
        }
        __syncthreads();  // scan done before half re-stage
    }
    m_d[part][ql][0] = b0; m_d[part][ql][1] = b1; m_d[part][ql][2] = b2;
    m_i[part][ql][0] = i0; m_i[part][ql][1] = i1; m_i[part][ql][2] = i2;
    __syncthreads();

    // merge 4x3 partials -> top-3, lexicographic (sq, idx). Parts scan
    // disjoint ranges so all 12 entries are distinct candidates.
    if (tid < 64) {
        float c0 = 1e30f, c1 = 1e30f, c2 = 1e30f;
        int a0 = 0x7fffffff, a1 = 0x7fffffff, a2 = 0x7fffffff;
#pragma unroll
        for (int pp = 0; pp < 4; pp++) {
#pragma unroll
            for (int k = 0; k < 3; k++) {
                float d = m_d[pp][tid][k];
                int ix = m_i[pp][tid][k];
                if (d < c2 || (d == c2 && ix < a2)) {
                    if (d < c1 || (d == c1 && ix < a1)) {
                        c2 = c1; a2 = a1;
                        if (d < c0 || (d == c0 && ix < a0)) { c1 = c0; a1 = a0; c0 = d; a0 = ix; }
                        else                                { c1 = d; a1 = ix; }
                    } else { c2 = d; a2 = ix; }
                }
            }
        }
        // exact reference math for winners: d = sqrt(max(sq,0)), clamp 1e-10
        float e0 = sqrtf(fmaxf(c0, 0.0f));
        float e1 = sqrtf(fmaxf(c1, 0.0f));
        float e2 = sqrtf(fmaxf(c2, 0.0f));
        float kd0 = fmaxf(e0, 1e-10f), kd1 = fmaxf(e1, 1e-10f), kd2 = fmaxf(e2, 1e-10f);
        float w0 = __fdiv_rn(1.0f, kd0), w1 = __fdiv_rn(1.0f, kd1), w2 = __fdiv_rn(1.0f, kd2);
        float wsum = __fadd_rn(__fadd_rn(w0, w1), w2);
        s_idx[tid][0] = a0; s_idx[tid][1] = a1; s_idx[tid][2] = a2;
        s_w[tid][0] = __fdiv_rn(w0, wsum);
        s_w[tid][1] = __fdiv_rn(w1, wsum);
        s_w[tid][2] = __fdiv_rn(w2, wsum);
    }
    __syncthreads();

    // gather: wave w handles queries p = w, w+4, ...; lane l covers channels
    // [4l, 4l+4) as ushort4 (8 B/lane, coalesced 512 B/wave).
    int l = tid & 63;
    const u16* base = P2T + (long)b * N2 * C2;
    for (int p = part; p < 64; p += 4) {
        int j0 = s_idx[p][0], j1 = s_idx[p][1], j2 = s_idx[p][2];  // broadcast
        float f0 = s_w[p][0], f1 = s_w[p][1], f2 = s_w[p][2];
        ushort4 r0 = *(const ushort4*)&base[(long)j0 * C2 + l * 4];
        ushort4 r1 = *(const ushort4*)&base[(long)j1 * C2 + l * 4];
        ushort4 r2 = *(const ushort4*)&base[(long)j2 * C2 + l * 4];
        ushort4 o;
        o.x = f2bf(__fadd_rn(__fadd_rn(__fmul_rn(bf2f(r0.x), f0), __fmul_rn(bf2f(r1.x), f1)),
                             __fmul_rn(bf2f(r2.x), f2)));
        o.y = f2bf(__fadd_rn(__fadd_rn(__fmul_rn(bf2f(r0.y), f0), __fmul_rn(bf2f(r1.y), f1)),
                             __fmul_rn(bf2f(r2.y), f2)));
        o.z = f2bf(__fadd_rn(__fadd_rn(__fmul_rn(bf2f(r0.z), f0), __fmul_rn(bf2f(r1.z), f1)),
                             __fmul_rn(bf2f(r2.z), f2)));
        o.w = f2bf(__fadd_rn(__fadd_rn(__fmul_rn(bf2f(r0.w), f0), __fmul_rn(bf2f(r1.w), f1)),
                             __fmul_rn(bf2f(r2.w), f2)));
        *(ushort4*)&X[(long)(b * N1 + n0 + p) * 384 + 128 + l * 4] = o;
    }
}

// ---------------------------------------------------------------------------
// bf16 MFMA GEMM (R5 form, R8: grid flipped to (ncol_tiles, nrow_tiles) so
// adjacent dispatches share the A-tile -> second X read hits L2 not HBM).
// ASYNC: global_load_lds w16 + XOR col swizzle. Else: VGPR staging + fused BN.
// Epilogue: bias add, bf16 store, per-channel sum/sumsq via atomics.
// ---------------------------------------------------------------------------
template <int KDIM, bool BN_IN, bool ASYNC>
__global__ __launch_bounds__(256) void gemm_bn(const u16* __restrict__ A,
                                               const u16* __restrict__ Bw,
                                               const float* __restrict__ bias,
                                               const float* __restrict__ g_in_sum,
                                               const float* __restrict__ g_in_ssq,
                                               const float* __restrict__ gamma_in,
                                               const float* __restrict__ beta_in,
                                               u16* __restrict__ Yout, int Ntot,
                                               float* __restrict__ g_out_sum,
                                               float* __restrict__ g_out_ssq) {
    constexpr int LD = ASYNC ? 32 : 40;
    __shared__ __align__(16) u16 Al[128 * LD];
    __shared__ __align__(16) u16 Bl[128 * LD];
    __shared__ float s_stats[256];
    __shared__ float s_scale[BN_IN ? KDIM : 2];
    __shared__ float s_shift[BN_IN ? KDIM : 2];

    int tid = threadIdx.x;
    long s0 = (long)blockIdx.y * 128;   // row tile (R8: was blockIdx.x)
    int o0 = blockIdx.x * 128;          // col tile (R8: was blockIdx.y)

    s_stats[tid] = 0.0f;
    if constexpr (BN_IN) {
        for (int k = tid; k < KDIM; k += 256) {
            float mu = g_in_sum[k] * (1.0f / 65536.0f);
            float var = g_in_ssq[k] * (1.0f / 65536.0f) - mu * mu;
            float rs = rsqrtf(var + 1e-5f);
            float sc = gamma_in[k] * rs;
            s_scale[k] = sc;
            s_shift[k] = beta_in[k] - mu * sc;
        }
    }
    int wid = tid >> 6, lane = tid & 63;
    int wm = wid >> 1, wn = wid & 1;
    int q = lane >> 4, l16 = lane & 15;

    f32x4 acc[4][4];
#pragma unroll
    for (int mi = 0; mi < 4; mi++)
#pragma unroll
        for (int ni = 0; ni < 4; ni++) acc[mi][ni] = (f32x4){0.f, 0.f, 0.f, 0.f};

    int rbase0 = wid * 32;
    int rsub = lane >> 2;
    int colsw = (((lane & 3) ^ (rsub & 3)) << 3);
    const u16* gA0 = A + (s0 + rbase0 + rsub) * KDIM + colsw;
    const u16* gA1 = gA0 + (long)16 * KDIM;
    const u16* gB0 = Bw + (long)(o0 + rbase0 + rsub) * KDIM + colsw;
    const u16* gB1 = gB0 + (long)16 * KDIM;
    u16* lA0 = &Al[rbase0 * 32];
    u16* lA1 = &Al[(rbase0 + 16) * 32];
    u16* lB0 = &Bl[rbase0 * 32];
    u16* lB1 = &Bl[(rbase0 + 16) * 32];
    int qA = ASYNC ? (q ^ (l16 & 3)) : q;

    __syncthreads();

    for (int kt = 0; kt < KDIM; kt += 32) {
        if constexpr (ASYNC) {
            gl_lds16(gA0 + kt, lA0);
            gl_lds16(gA1 + kt, lA1);
            gl_lds16(gB0 + kt, lB0);
            gl_lds16(gB1 + kt, lB1);
        } else {
#pragma unroll
            for (int cc = 0; cc < 2; cc++) {
                int ci = tid + cc * 256;
                int row = ci >> 2;
                int kc = (ci & 3) << 3;
                union { uint4 u; u16 h[8]; } va;
                va.u = *(const uint4*)(A + (s0 + row) * KDIM + kt + kc);
                if constexpr (BN_IN) {
#pragma unroll
                    for (int j = 0; j < 8; j++) {
                        float f = bf2f(va.h[j]);
                        f = fmaxf(fmaf(f, s_scale[kt + kc + j], s_shift[kt + kc + j]), 0.0f);
                        va.h[j] = f2bf(f);
                    }
                }
                *(uint4*)&Al[row * LD + kc] = va.u;
                *(uint4*)&Bl[row * LD + kc] = *(const uint4*)(Bw + (long)(o0 + row) * KDIM + kt + kc);
            }
        }
        __syncthreads();
        bf16x8 af[4], bfr[4];
#pragma unroll
        for (int mi = 0; mi < 4; mi++)
            af[mi] = *(const bf16x8*)&Al[(wm * 64 + mi * 16 + l16) * LD + qA * 8];
#pragma unroll
        for (int ni = 0; ni < 4; ni++)
            bfr[ni] = *(const bf16x8*)&Bl[(wn * 64 + ni * 16 + l16) * LD + qA * 8];
#pragma unroll
        for (int mi = 0; mi < 4; mi++)
#pragma unroll
            for (int ni = 0; ni < 4; ni++)
                acc[mi][ni] = __builtin_amdgcn_mfma_f32_16x16x32_bf16(af[mi], bfr[ni],
                                                                      acc[mi][ni], 0, 0, 0);
        __syncthreads();
    }

#pragma unroll
    for (int ni = 0; ni < 4; ni++) {
        int coll = wn * 64 + ni * 16 + l16;
        int col = o0 + coll;
        float bz = bias[col];
        float s1 = 0.0f, s2 = 0.0f;
#pragma unroll
        for (int mi = 0; mi < 4; mi++) {
#pragma unroll
            for (int r = 0; r < 4; r++) {
                float v = acc[mi][ni][r] + bz;
                s1 += v;
                s2 += v * v;
                long row = s0 + wm * 64 + mi * 16 + q * 4 + r;
                Yout[row * Ntot + col] = f2bf(v);
            }
        }
        s1 += __shfl_xor(s1, 16, 64);
        s1 += __shfl_xor(s1, 32, 64);
        s2 += __shfl_xor(s2, 16, 64);
        s2 += __shfl_xor(s2, 32, 64);
        if (q == 0) {
            atomicAdd(&s_stats[coll], s1);
            atomicAdd(&s_stats[128 + coll], s2);
        }
    }
    __syncthreads();
    if (tid < 128) {
        atomicAdd(&g_out_sum[o0 + tid], s_stats[tid]);
        atomicAdd(&g_out_ssq[o0 + tid], s_stats[128 + tid]);
    }
}

// ---------------------------------------------------------------------------
// final BN+ReLU + transpose to [B][128][N1] fp32 (Y1 bf16, 16B reads)
// ---------------------------------------------------------------------------
__global__ __launch_bounds__(256) void finalize_k(const u16* __restrict__ Y1,
                                                  const float* __restrict__ g_sum,
                                                  const float* __restrict__ g_ssq,
                                                  const float* __restrict__ gamma,
                                                  const float* __restrict__ beta,
                                                  float* __restrict__ out) {
    __shared__ float s_scale[128], s_shift[128];
    int tid = threadIdx.x;
    if (tid < 128) {
        float mu = g_sum[tid] * (1.0f / 65536.0f);
        float var = g_ssq[tid] * (1.0f / 65536.0f) - mu * mu;
        float rs = rsqrtf(var + 1e-5f);
        float sc = gamma[tid] * rs;
        s_scale[tid] = sc;
        s_shift[tid] = beta[tid] - mu * sc;
    }
    __syncthreads();
    long s = (long)blockIdx.x * 256 + tid;
    int b = (int)(s >> 13);
    int n = (int)(s & 8191);
    const u16* yrow = Y1 + s * 128;
    float* obase = out + (long)b * 128 * 8192 + n;
#pragma unroll
    for (int oc = 0; oc < 128; oc += 8) {
        union { uint4 u; u16 h[8]; } va;
        va.u = *(const uint4*)&yrow[oc];
#pragma unroll
        for (int k = 0; k < 8; k++) {
            int o = oc + k;
            float v = fmaxf(fmaf(bf2f(va.h[k]), s_scale[o], s_shift[o]), 0.0f);
            obase[(long)o * 8192] = v;
        }
    }
}

// ---------------------------------------------------------------------------
// launch (R8: 5 dispatches, was 7)
// ---------------------------------------------------------------------------
extern "C" void kernel_launch(void* const* d_in, const int* in_sizes, int n_in,
                              void* d_out, int out_size, void* d_ws, size_t ws_size,
                              hipStream_t stream) {
    const float* xyz1    = (const float*)d_in[0];
    const float* xyz2    = (const float*)d_in[1];
    const float* points1 = (const float*)d_in[2];
    const float* points2 = (const float*)d_in[3];
    const float* w0 = (const float*)d_in[4];
    const float* b0 = (const float*)d_in[5];
    const float* gamma0 = (const float*)d_in[6];
    const float* beta0 = (const float*)d_in[7];
    const float* w1 = (const float*)d_in[8];
    const float* b1 = (const float*)d_in[9];
    const float* gamma1 = (const float*)d_in[10];
    const float* beta1 = (const float*)d_in[11];
    float* out = (float*)d_out;

    char* ws = (char*)d_ws;
    u16* X       = (u16*)(ws + 0);             // 65536 x 384 bf16 = 50,331,648
    u16* P2T     = (u16*)(ws + 50331648);      // 8,388,608
    u16* w0b     = (u16*)(ws + 58720256);      // 196,608
    u16* w1b     = (u16*)(ws + 58916864);      // 65,536
    u16* Y0      = (u16*)(ws + 58982400);      // 33,554,432
    u16* Y1b     = (u16*)(ws + 92536832);      // 16,777,216
    float* stats = (float*)(ws + 109314048);   // 3,072
    if (ws_size < 109317120) return;
    float* gsum0 = stats;
    float* gss0  = stats + 256;
    float* gsum1 = stats + 512;
    float* gss1  = stats + 640;

    preproc<<<12801, 256, 0, stream>>>(w0, w1, points1, points2, w0b, w1b, X, P2T, stats);
    knn_interp<<<dim3(128, 8), 256, 0, stream>>>(xyz1, xyz2, P2T, X);
    gemm_bn<384, false, true><<<dim3(2, 512), 256, 0, stream>>>(
        X, w0b, b0, nullptr, nullptr, nullptr, nullptr, Y0, 256, gsum0, gss0);
    gemm_bn<256, true, false><<<dim3(1, 512), 256, 0, stream>>>(
        Y0, w1b, b1, gsum0, gss0, gamma0, beta0, Y1b, 128, gsum1, gss1);
    finalize_k<<<256, 256, 0, stream>>>(Y1b, gsum1, gss1, gamma1, beta1, out);
}

// Round 9
// 250.878 us; speedup vs baseline: 1.8792x; 1.0285x over previous
//
#include <hip/hip_runtime.h>
#include <cstdint>

using u16 = unsigned short;
typedef short bf16x8 __attribute__((ext_vector_type(8)));
typedef float f32x4 __attribute__((ext_vector_type(4)));

__device__ __forceinline__ float bf2f(u16 h) {
    union { unsigned u; float f; } x;
    x.u = ((unsigned)h) << 16;
    return x.f;
}
__device__ __forceinline__ u16 f2bf(float f) {
    union { float f; unsigned u; } x;
    x.f = f;
    unsigned r = x.u + 0x7fffu + ((x.u >> 16) & 1u);
    return (u16)(r >> 16);
}

// async global->LDS, 16B per lane; LDS dest is wave-uniform base + lane*16
__device__ __forceinline__ void gl_lds16(const u16* g, u16* l) {
    __builtin_amdgcn_global_load_lds((const __attribute__((address_space(1))) void*)g,
                                     (__attribute__((address_space(3))) void*)l, 16, 0, 0);
}

#define N1 8192
#define N2 2048
#define C2 256

// ---------------------------------------------------------------------------
// fused preproc (R8): points1/points2 transposes + w0/w1 cvt + stats zero.
// ---------------------------------------------------------------------------
__device__ __forceinline__ void tr_tile(const float* __restrict__ src,
                                        u16* __restrict__ dst,
                                        int C, int N, int ds, int b, int n0, int c0,
                                        int tid, float (*tile)[33]) {
    int tx = tid & 31, ty = tid >> 5;  // 32 x 8
    const float* s = src + (long)b * C * N;
#pragma unroll
    for (int i = 0; i < 4; i++) {
        int c = ty + i * 8;
        tile[c][tx] = s[(long)(c0 + c) * N + n0 + tx];
    }
    __syncthreads();
    u16* d = dst + (long)b * N * ds;
#pragma unroll
    for (int i = 0; i < 4; i++) {
        int n = ty + i * 8;
        d[(long)(n0 + n) * ds + c0 + tx] = f2bf(tile[tx][n]);
    }
}

__global__ __launch_bounds__(256) void preproc(const float* __restrict__ w0,
                                               const float* __restrict__ w1,
                                               const float* __restrict__ points1,
                                               const float* __restrict__ points2,
                                               u16* __restrict__ w0b,
                                               u16* __restrict__ w1b,
                                               u16* __restrict__ X,
                                               u16* __restrict__ P2T,
                                               float* __restrict__ stats) {
    __shared__ float tile[32][33];
    int bid = blockIdx.x, tid = threadIdx.x;
    if (bid < 8192) {
        int nb = bid & 255, cb = (bid >> 8) & 3, b = bid >> 10;
        tr_tile(points1, X, 128, 8192, 384, b, nb * 32, cb * 32, tid, tile);
    } else if (bid < 12288) {
        int t = bid - 8192;
        int nb = t & 63, cb = (t >> 6) & 7, b = t >> 9;
        tr_tile(points2, P2T, 256, 2048, 256, b, nb * 32, cb * 32, tid, tile);
    } else if (bid < 12672) {
        int i = (bid - 12288) * 256 + tid;
        w0b[i] = f2bf(w0[i]);
    } else if (bid < 12800) {
        int i = (bid - 12672) * 256 + tid;
        w1b[i] = f2bf(w1[i]);
    } else {
        for (int i = tid; i < 768; i += 256) stats[i] = 0.0f;
    }
}

// ---------------------------------------------------------------------------
// kNN(3) + interpolation — R9: 8 scanner waves (512 thr) for occupancy.
// Scan BODY is the R3 cascade VERBATIM (measured best at 80.6/77.9; R4/R5/R6
// rewrites all regressed — body is frozen). Structure: 2 staged halves of
// 1024 candidates (16KB), each wave scans 128 per half (disjoint ascending
// index ranges; strict < keeps earlier index on ties == reference), 8x3
// lexicographic merge. LDS ~30KB -> 5 blocks/CU by LDS; grid 1024 = 4/CU
// -> 32 waves/CU theoretical.
// ---------------------------------------------------------------------------
__global__ __launch_bounds__(512) void knn_interp(const float* __restrict__ xyz1,
                                                  const float* __restrict__ xyz2,
                                                  const u16* __restrict__ P2T,  // [B][N2][C2]
                                                  u16* __restrict__ X) {       // [B*N1][384]
    __shared__ float4 pts[N2 / 2];      // 16384 B (half-staged)
    __shared__ float m_d[8][64][3];     // 6144 B partial top-3 (squared dist)
    __shared__ int   m_i[8][64][3];     // 6144 B
    __shared__ int   s_idx[64][3];
    __shared__ float s_w[64][3];
    int b = blockIdx.y;
    int n0 = blockIdx.x * 64;
    int tid = threadIdx.x;
    int ql = tid & 63;       // query within block
    int part = tid >> 6;     // candidate partition 0..7 (== wave id)

    int n = n0 + ql;
    float px = xyz1[((long)b * N1 + n) * 3 + 0];
    float py = xyz1[((long)b * N1 + n) * 3 + 1];
    float pz = xyz1[((long)b * N1 + n) * 3 + 2];
    float psq = __fadd_rn(__fadd_rn(__fmul_rn(px, px), __fmul_rn(py, py)), __fmul_rn(pz, pz));

    float b0 = 1e30f, b1 = 1e30f, b2 = 1e30f;
    int i0 = 0, i1 = 0, i2 = 0;

    for (int half = 0; half < 2; half++) {
        // stage this half of xyz2[b] with squared norm (ref formula, no FMA)
        for (int j = tid; j < N2 / 2; j += 512) {
            int jg = half * (N2 / 2) + j;
            float x = xyz2[((long)b * N2 + jg) * 3 + 0];
            float y = xyz2[((long)b * N2 + jg) * 3 + 1];
            float z = xyz2[((long)b * N2 + jg) * 3 + 2];
            float nsq = __fadd_rn(__fadd_rn(__fmul_rn(x, x), __fmul_rn(y, y)), __fmul_rn(z, z));
            pts[j] = make_float4(x, y, z, nsq);
        }
        __syncthreads();

        // scan this wave's 128-candidate slice (R3 body verbatim)
        int jbeg = half * (N2 / 2) + part * (N2 / 16);
        const float4* lp = &pts[part * (N2 / 16)];
#pragma unroll 8
        for (int jj = 0; jj < N2 / 16; jj++) {
            int j = jbeg + jj;
            float4 p = lp[jj];  // wave-uniform -> LDS broadcast
            float dot = __fadd_rn(__fadd_rn(__fmul_rn(px, p.x), __fmul_rn(py, p.y)),
                                  __fmul_rn(pz, p.z));
            float sq = __fsub_rn(__fadd_rn(psq, p.w), __fmul_rn(2.0f, dot));
            if (sq < b2) {
                if (sq < b1) {
                    b2 = b1; i2 = i1;
                    if (sq < b0) { b1 = b0; i1 = i0; b0 = sq; i0 = j; }
                    else         { b1 = sq; i1 = j; }
                } else { b2 = sq; i2 = j; }
            }
        }
        __syncthreads();  // scan done before half re-stage
    }
    m_d[part][ql][0] = b0; m_d[part][ql][1] = b1; m_d[part][ql][2] = b2;
    m_i[part][ql][0] = i0; m_i[part][ql][1] = i1; m_i[part][ql][2] = i2;
    __syncthreads();

    // merge 8x3 partials -> top-3, lexicographic (sq, idx). Parts scan
    // disjoint ranges so all 24 entries are distinct candidates.
    if (tid < 64) {
        float c0 = 1e30f, c1 = 1e30f, c2 = 1e30f;
        int a0 = 0x7fffffff, a1 = 0x7fffffff, a2 = 0x7fffffff;
#pragma unroll
        for (int pp = 0; pp < 8; pp++) {
#pragma unroll
            for (int k = 0; k < 3; k++) {
                float d = m_d[pp][tid][k];
                int ix = m_i[pp][tid][k];
                if (d < c2 || (d == c2 && ix < a2)) {
                    if (d < c1 || (d == c1 && ix < a1)) {
                        c2 = c1; a2 = a1;
                        if (d < c0 || (d == c0 && ix < a0)) { c1 = c0; a1 = a0; c0 = d; a0 = ix; }
                        else                                { c1 = d; a1 = ix; }
                    } else { c2 = d; a2 = ix; }
                }
            }
        }
        // exact reference math for winners: d = sqrt(max(sq,0)), clamp 1e-10
        float e0 = sqrtf(fmaxf(c0, 0.0f));
        float e1 = sqrtf(fmaxf(c1, 0.0f));
        float e2 = sqrtf(fmaxf(c2, 0.0f));
        float kd0 = fmaxf(e0, 1e-10f), kd1 = fmaxf(e1, 1e-10f), kd2 = fmaxf(e2, 1e-10f);
        float w0 = __fdiv_rn(1.0f, kd0), w1 = __fdiv_rn(1.0f, kd1), w2 = __fdiv_rn(1.0f, kd2);
        float wsum = __fadd_rn(__fadd_rn(w0, w1), w2);
        s_idx[tid][0] = a0; s_idx[tid][1] = a1; s_idx[tid][2] = a2;
        s_w[tid][0] = __fdiv_rn(w0, wsum);
        s_w[tid][1] = __fdiv_rn(w1, wsum);
        s_w[tid][2] = __fdiv_rn(w2, wsum);
    }
    __syncthreads();

    // gather: wave w handles queries p = w, w+8, ...; lane l covers channels
    // [4l, 4l+4) as ushort4 (8 B/lane, coalesced 512 B/wave).
    int l = tid & 63;
    const u16* base = P2T + (long)b * N2 * C2;
    for (int p = part; p < 64; p += 8) {
        int j0 = s_idx[p][0], j1 = s_idx[p][1], j2 = s_idx[p][2];  // broadcast
        float f0 = s_w[p][0], f1 = s_w[p][1], f2 = s_w[p][2];
        ushort4 r0 = *(const ushort4*)&base[(long)j0 * C2 + l * 4];
        ushort4 r1 = *(const ushort4*)&base[(long)j1 * C2 + l * 4];
        ushort4 r2 = *(const ushort4*)&base[(long)j2 * C2 + l * 4];
        ushort4 o;
        o.x = f2bf(__fadd_rn(__fadd_rn(__fmul_rn(bf2f(r0.x), f0), __fmul_rn(bf2f(r1.x), f1)),
                             __fmul_rn(bf2f(r2.x), f2)));
        o.y = f2bf(__fadd_rn(__fadd_rn(__fmul_rn(bf2f(r0.y), f0), __fmul_rn(bf2f(r1.y), f1)),
                             __fmul_rn(bf2f(r2.y), f2)));
        o.z = f2bf(__fadd_rn(__fadd_rn(__fmul_rn(bf2f(r0.z), f0), __fmul_rn(bf2f(r1.z), f1)),
                             __fmul_rn(bf2f(r2.z), f2)));
        o.w = f2bf(__fadd_rn(__fadd_rn(__fmul_rn(bf2f(r0.w), f0), __fmul_rn(bf2f(r1.w), f1)),
                             __fmul_rn(bf2f(r2.w), f2)));
        *(ushort4*)&X[(long)(b * N1 + n0 + p) * 384 + 128 + l * 4] = o;
    }
}

// ---------------------------------------------------------------------------
// bf16 MFMA GEMM. R9: ASYNC path stages BK=64 (two 32-K sub-tiles) per
// barrier pair -> 6 barrier pairs instead of 12 at K=384. Accumulation order
// unchanged (ascending k) => bitwise-identical output. LDS 33KB -> 4 blk/CU.
// Non-ASYNC (gemm1): BK=32 VGPR staging + fused input BN+ReLU (stride-40).
// Epilogue: bias add, bf16 store, per-channel sum/sumsq via atomics.
// ---------------------------------------------------------------------------
template <int KDIM, bool BN_IN, bool ASYNC>
__global__ __launch_bounds__(256) void gemm_bn(const u16* __restrict__ A,
                                               const u16* __restrict__ Bw,
                                               const float* __restrict__ bias,
                                               const float* __restrict__ g_in_sum,
                                               const float* __restrict__ g_in_ssq,
                                               const float* __restrict__ gamma_in,
                                               const float* __restrict__ beta_in,
                                               u16* __restrict__ Yout, int Ntot,
                                               float* __restrict__ g_out_sum,
                                               float* __restrict__ g_out_ssq) {
    constexpr int LDSZ = ASYNC ? 2 * 128 * 32 : 128 * 40;  // u16 elems
    constexpr int SUB = 128 * 32;                          // sub-tile size (ASYNC)
    __shared__ __align__(16) u16 Al[LDSZ];
    __shared__ __align__(16) u16 Bl[LDSZ];
    __shared__ float s_stats[256];
    __shared__ float s_scale[BN_IN ? KDIM : 2];
    __shared__ float s_shift[BN_IN ? KDIM : 2];

    int tid = threadIdx.x;
    long s0 = (long)blockIdx.y * 128;   // row tile
    int o0 = blockIdx.x * 128;          // col tile

    s_stats[tid] = 0.0f;
    if constexpr (BN_IN) {
        for (int k = tid; k < KDIM; k += 256) {
            float mu = g_in_sum[k] * (1.0f / 65536.0f);
            float var = g_in_ssq[k] * (1.0f / 65536.0f) - mu * mu;
            float rs = rsqrtf(var + 1e-5f);
            float sc = gamma_in[k] * rs;
            s_scale[k] = sc;
            s_shift[k] = beta_in[k] - mu * sc;
        }
    }
    int wid = tid >> 6, lane = tid & 63;
    int wm = wid >> 1, wn = wid & 1;
    int q = lane >> 4, l16 = lane & 15;

    f32x4 acc[4][4];
#pragma unroll
    for (int mi = 0; mi < 4; mi++)
#pragma unroll
        for (int ni = 0; ni < 4; ni++) acc[mi][ni] = (f32x4){0.f, 0.f, 0.f, 0.f};

    int rbase0 = wid * 32;
    int rsub = lane >> 2;
    int colsw = (((lane & 3) ^ (rsub & 3)) << 3);
    const u16* gA0 = A + (s0 + rbase0 + rsub) * KDIM + colsw;
    const u16* gA1 = gA0 + (long)16 * KDIM;
    const u16* gB0 = Bw + (long)(o0 + rbase0 + rsub) * KDIM + colsw;
    const u16* gB1 = gB0 + (long)16 * KDIM;
    u16* lA0 = &Al[rbase0 * 32];
    u16* lA1 = &Al[(rbase0 + 16) * 32];
    u16* lB0 = &Bl[rbase0 * 32];
    u16* lB1 = &Bl[(rbase0 + 16) * 32];
    int qA = ASYNC ? (q ^ (l16 & 3)) : q;

    __syncthreads();

    if constexpr (ASYNC) {
        for (int kt = 0; kt < KDIM; kt += 64) {
#pragma unroll
            for (int sub = 0; sub < 2; sub++) {
                int ko = kt + sub * 32;
                gl_lds16(gA0 + ko, lA0 + sub * SUB);
                gl_lds16(gA1 + ko, lA1 + sub * SUB);
                gl_lds16(gB0 + ko, lB0 + sub * SUB);
                gl_lds16(gB1 + ko, lB1 + sub * SUB);
            }
            __syncthreads();
#pragma unroll
            for (int sub = 0; sub < 2; sub++) {
                bf16x8 af[4], bfr[4];
#pragma unroll
                for (int mi = 0; mi < 4; mi++)
                    af[mi] = *(const bf16x8*)&Al[sub * SUB + (wm * 64 + mi * 16 + l16) * 32 + qA * 8];
#pragma unroll
                for (int ni = 0; ni < 4; ni++)
                    bfr[ni] = *(const bf16x8*)&Bl[sub * SUB + (wn * 64 + ni * 16 + l16) * 32 + qA * 8];
#pragma unroll
                for (int mi = 0; mi < 4; mi++)
#pragma unroll
                    for (int ni = 0; ni < 4; ni++)
                        acc[mi][ni] = __builtin_amdgcn_mfma_f32_16x16x32_bf16(af[mi], bfr[ni],
                                                                              acc[mi][ni], 0, 0, 0);
            }
            __syncthreads();
        }
    } else {
        for (int kt = 0; kt < KDIM; kt += 32) {
#pragma unroll
            for (int cc = 0; cc < 2; cc++) {
                int ci = tid + cc * 256;
                int row = ci >> 2;
                int kc = (ci & 3) << 3;
                union { uint4 u; u16 h[8]; } va;
                va.u = *(const uint4*)(A + (s0 + row) * KDIM + kt + kc);
                if constexpr (BN_IN) {
#pragma unroll
                    for (int j = 0; j < 8; j++) {
                        float f = bf2f(va.h[j]);
                        f = fmaxf(fmaf(f, s_scale[kt + kc + j], s_shift[kt + kc + j]), 0.0f);
                        va.h[j] = f2bf(f);
                    }
                }
                *(uint4*)&Al[row * 40 + kc] = va.u;
                *(uint4*)&Bl[row * 40 + kc] = *(const uint4*)(Bw + (long)(o0 + row) * KDIM + kt + kc);
            }
            __syncthreads();
            bf16x8 af[4], bfr[4];
#pragma unroll
            for (int mi = 0; mi < 4; mi++)
                af[mi] = *(const bf16x8*)&Al[(wm * 64 + mi * 16 + l16) * 40 + qA * 8];
#pragma unroll
            for (int ni = 0; ni < 4; ni++)
                bfr[ni] = *(const bf16x8*)&Bl[(wn * 64 + ni * 16 + l16) * 40 + qA * 8];
#pragma unroll
            for (int mi = 0; mi < 4; mi++)
#pragma unroll
                for (int ni = 0; ni < 4; ni++)
                    acc[mi][ni] = __builtin_amdgcn_mfma_f32_16x16x32_bf16(af[mi], bfr[ni],
                                                                          acc[mi][ni], 0, 0, 0);
            __syncthreads();
        }
    }

#pragma unroll
    for (int ni = 0; ni < 4; ni++) {
        int coll = wn * 64 + ni * 16 + l16;
        int col = o0 + coll;
        float bz = bias[col];
        float s1 = 0.0f, s2 = 0.0f;
#pragma unroll
        for (int mi = 0; mi < 4; mi++) {
#pragma unroll
            for (int r = 0; r < 4; r++) {
                float v = acc[mi][ni][r] + bz;
                s1 += v;
                s2 += v * v;
                long row = s0 + wm * 64 + mi * 16 + q * 4 + r;
                Yout[row * Ntot + col] = f2bf(v);
            }
        }
        s1 += __shfl_xor(s1, 16, 64);
        s1 += __shfl_xor(s1, 32, 64);
        s2 += __shfl_xor(s2, 16, 64);
        s2 += __shfl_xor(s2, 32, 64);
        if (q == 0) {
            atomicAdd(&s_stats[coll], s1);
            atomicAdd(&s_stats[128 + coll], s2);
        }
    }
    __syncthreads();
    if (tid < 128) {
        atomicAdd(&g_out_sum[o0 + tid], s_stats[tid]);
        atomicAdd(&g_out_ssq[o0 + tid], s_stats[128 + tid]);
    }
}

// ---------------------------------------------------------------------------
// final BN+ReLU + transpose to [B][128][N1] fp32 (Y1 bf16, 16B reads)
// ---------------------------------------------------------------------------
__global__ __launch_bounds__(256) void finalize_k(const u16* __restrict__ Y1,
                                                  const float* __restrict__ g_sum,
                                                  const float* __restrict__ g_ssq,
                                                  const float* __restrict__ gamma,
                                                  const float* __restrict__ beta,
                                                  float* __restrict__ out) {
    __shared__ float s_scale[128], s_shift[128];
    int tid = threadIdx.x;
    if (tid < 128) {
        float mu = g_sum[tid] * (1.0f / 65536.0f);
        float var = g_ssq[tid] * (1.0f / 65536.0f) - mu * mu;
        float rs = rsqrtf(var + 1e-5f);
        float sc = gamma[tid] * rs;
        s_scale[tid] = sc;
        s_shift[tid] = beta[tid] - mu * sc;
    }
    __syncthreads();
    long s = (long)blockIdx.x * 256 + tid;
    int b = (int)(s >> 13);
    int n = (int)(s & 8191);
    const u16* yrow = Y1 + s * 128;
    float* obase = out + (long)b * 128 * 8192 + n;
#pragma unroll
    for (int oc = 0; oc < 128; oc += 8) {
        union { uint4 u; u16 h[8]; } va;
        va.u = *(const uint4*)&yrow[oc];
#pragma unroll
        for (int k = 0; k < 8; k++) {
            int o = oc + k;
            float v = fmaxf(fmaf(bf2f(va.h[k]), s_scale[o], s_shift[o]), 0.0f);
            obase[(long)o * 8192] = v;
        }
    }
}

// ---------------------------------------------------------------------------
// launch (5 dispatches)
// ---------------------------------------------------------------------------
extern "C" void kernel_launch(void* const* d_in, const int* in_sizes, int n_in,
                              void* d_out, int out_size, void* d_ws, size_t ws_size,
                              hipStream_t stream) {
    const float* xyz1    = (const float*)d_in[0];
    const float* xyz2    = (const float*)d_in[1];
    const float* points1 = (const float*)d_in[2];
    const float* points2 = (const float*)d_in[3];
    const float* w0 = (const float*)d_in[4];
    const float* b0 = (const float*)d_in[5];
    const float* gamma0 = (const float*)d_in[6];
    const float* beta0 = (const float*)d_in[7];
    const float* w1 = (const float*)d_in[8];
    const float* b1 = (const float*)d_in[9];
    const float* gamma1 = (const float*)d_in[10];
    const float* beta1 = (const float*)d_in[11];
    float* out = (float*)d_out;

    char* ws = (char*)d_ws;
    u16* X       = (u16*)(ws + 0);             // 65536 x 384 bf16 = 50,331,648
    u16* P2T     = (u16*)(ws + 50331648);      // 8,388,608
    u16* w0b     = (u16*)(ws + 58720256);      // 196,608
    u16* w1b     = (u16*)(ws + 58916864);      // 65,536
    u16* Y0      = (u16*)(ws + 58982400);      // 33,554,432
    u16* Y1b     = (u16*)(ws + 92536832);      // 16,777,216
    float* stats = (float*)(ws + 109314048);   // 3,072
    if (ws_size < 109317120) return;
    float* gsum0 = stats;
    float* gss0  = stats + 256;
    float* gsum1 = stats + 512;
    float* gss1  = stats + 640;

    preproc<<<12801, 256, 0, stream>>>(w0, w1, points1, points2, w0b, w1b, X, P2T, stats);
    knn_interp<<<dim3(128, 8), 512, 0, stream>>>(xyz1, xyz2, P2T, X);
    gemm_bn<384, false, true><<<dim3(2, 512), 256, 0, stream>>>(
        X, w0b, b0, nullptr, nullptr, nullptr, nullptr, Y0, 256, gsum0, gss0);
    gemm_bn<256, true, false><<<dim3(1, 512), 256, 0, stream>>>(
        Y0, w1b, b1, gsum0, gss0, gamma0, beta0, Y1b, 128, gsum1, gss1);
    finalize_k<<<256, 256, 0, stream>>>(Y1b, gsum1, gss1, gamma1, beta1, out);
}